// Round 7
// baseline (354.590 us; speedup 1.0000x reference)
//
#include <hip/hip_runtime.h>
#include <hip/hip_bf16.h>
#include <math.h>

// ---------------------------------------------------------------------------
// JointAttention fp16 MFMA pipeline, 6 dispatches:
//   prep (fp32->fp16 x/ctx + pack W^T) -> proj (fused 5-job QKV GEMM, dbuf) ->
//   transpose_v -> flash attn (S^T, TK=64, SPLIT-K4, 32x32 MFMA, in-register
//   softmax, NO-LDS direct-global fragments) -> combine -> out GEMM (dbuf).
// R1: proj/out GEMM dbuf; setprio in attn.
// R2: attn single-buffer K/V + reg-staged prefetch: LDS 50->34.8KB.
// R3: attn on mfma_f32_32x32x16_f16: in-register P via permlane32_swap;
//     P_lds gone; LDS 16KB, VGPR 60 (+~48 acc).
// R4: split-K4 + bounds(256,8) -> acc spill regression (VGPR 32, 812MB).
// R5: split-K4 + bounds(256,4): no spill but NULL — occupancy still 4
//     waves/SIMD. Lesson: unified VGPR+AGPR (~124/wave) caps residency;
//     grid can't add waves. ~26% of cycles were barrier-lockstep stall.
// R6: attn LDS + __syncthreads DELETED. K/V fragments read directly from
//     global (kbuf/vt are already tiled fragment-addressable; verified the
//     stage-swizzle/reader-XOR cancel => linear addressing). Zero barriers:
//     waves drift freely; L1 shares tiles across the CU's blocks; L2 via
//     XCD-chunked block swizzle (qt fastest, 16 (bh,sp) splits = 4MB/XCD).
// R7: resubmit of R6 — bench died at container level (no kernel signal);
//     full OOB/hang audit found no fault source; treating as infra flake.
// Layouts:
//   qbuf [bh][2048][64]              (Q pre-scaled by 0.125*log2e)
//   kbuf [bh][kt64][ks2][tok64][32]  (linear; fragment = 16B @ tok*32+k16)
//   vbuf [bh][4096][64]  -> dead after transpose_v, reused as osplit sp0/1
//   vt   [bh][kt64][kks2][d64][32]   (linear fragment tiles)
//   osplit [sp&1][bh][2048][64] f16 x2 regions (vbuf | d_out)
//   lsplit [s4][bh][2048] f32 @ dead Wq^T region
// ---------------------------------------------------------------------------

typedef _Float16 f16;
typedef _Float16 f16x8 __attribute__((ext_vector_type(8)));
typedef _Float16 f16x4v __attribute__((ext_vector_type(4)));
typedef _Float16 f16x2 __attribute__((ext_vector_type(2)));
typedef float    f32x4 __attribute__((ext_vector_type(4)));
typedef float    f32x16 __attribute__((ext_vector_type(16)));
typedef unsigned u32x4v __attribute__((ext_vector_type(4)));

#define MFMA_F16(a, b, c)  __builtin_amdgcn_mfma_f32_16x16x32_f16((a), (b), (c), 0, 0, 0)
#define MFMA32_F16(a, b, c) __builtin_amdgcn_mfma_f32_32x32x16_f16((a), (b), (c), 0, 0, 0)

#define QSCALE 0.18033688011112042f   // 0.125 * log2(e)

__device__ __forceinline__ void glds16(const f16* g, f16* l) {
    __builtin_amdgcn_global_load_lds(
        (const __attribute__((address_space(1))) void*)g,
        (__attribute__((address_space(3))) void*)l, 16, 0, 0);
}

// RNE f32x2 -> packed f16x2
__device__ __forceinline__ unsigned pk16(float a, float b) {
    f16x2 t = { (f16)a, (f16)b };
    return __builtin_bit_cast(unsigned, t);
}

// ---------------------------------------------------------------------------
// prep: blocks [0,8192) convert x/ctx fp32->fp16; [8192,14336) pack 6 W^T
// ---------------------------------------------------------------------------
__global__ __launch_bounds__(256) void prep(
    const float4* __restrict__ x, const float4* __restrict__ ctx,
    f16x4v* __restrict__ xb, f16x4v* __restrict__ cb,
    const float* __restrict__ W0, const float* __restrict__ W1,
    const float* __restrict__ W2, const float* __restrict__ W3,
    const float* __restrict__ W4, const float* __restrict__ W5,
    f16* __restrict__ wt)
{
    if (blockIdx.x < 8192) {
        const int n4 = (2 * 2048 * 1024) / 4;
        int i = blockIdx.x * 256 + threadIdx.x;
        float4 v;
        f16x4v* dst;
        if (i < n4) { v = x[i];        dst = xb + i; }
        else        { v = ctx[i - n4]; dst = cb + (i - n4); }
        f16x4v h = { (f16)v.x, (f16)v.y, (f16)v.z, (f16)v.w };
        *dst = h;
        return;
    }
    const int idx = blockIdx.x - 8192;
    const int z = idx >> 10, rem = idx & 1023;
    const float* Ws[6] = { W0, W1, W2, W3, W4, W5 };
    const float* W = Ws[z];
    f16* Wt = wt + (size_t)z * (1024 * 1024);

    __shared__ float tile[32][33];
    const int tx = threadIdx.x & 31, ty = threadIdx.x >> 5;
    const int n0 = (rem & 31) * 32, k0 = (rem >> 5) * 32;

#pragma unroll
    for (int i = 0; i < 4; ++i) {
        int r = i * 8 + ty;
        tile[r][tx] = W[(size_t)(k0 + r) * 1024 + n0 + tx];
    }
    __syncthreads();
#pragma unroll
    for (int i = 0; i < 4; ++i) {
        int r = i * 8 + ty;
        Wt[(size_t)(n0 + r) * 1024 + k0 + tx] = (f16)tile[tx][r];
    }
}

// Shared GEMM prologue (128-row A tile, BN-row B tile, BK=32, swizzled glds)
#define GEMM_PROLOGUE(BN)                                                     \
    const int m0 = blockIdx.x * 128, n0 = blockIdx.y * (BN);                  \
    const int tid = threadIdx.x;                                              \
    const int w = tid >> 6, lane = tid & 63, quad = lane >> 4, l15 = lane & 15;\
    const int wm = (w >> 1) * 64, wn = (w & 1) * ((BN) / 2);                  \
    const int qsw = (quad ^ ((l15 >> 1) & 3)) * 8;                            \
    int gA[2], gB[(BN) / 64];                                                 \
    _Pragma("unroll")                                                         \
    for (int p = 0; p < 2; ++p) {                                             \
        int s = tid + p * 256;                                                \
        int r = (s >> 2) & 127, c = (s & 3) ^ ((s >> 3) & 3);                 \
        gA[p] = (m0 + r) * 1024 + c * 8;                                      \
    }                                                                         \
    _Pragma("unroll")                                                         \
    for (int p = 0; p < (BN) / 64; ++p) {                                     \
        int s = tid + p * 256;                                                \
        int r = (s >> 2) & ((BN) - 1), c = (s & 3) ^ ((s >> 3) & 3);          \
        gB[p] = (n0 + r) * 1024 + c * 8;                                      \
    }

// Stage K-chunk koff into LDS buffer `buf` (no barriers; caller owns sync)
#define GEMM_STAGE_TO(BN, buf, koff)                                          \
    _Pragma("unroll")                                                         \
    for (int p = 0; p < 2; ++p)                                               \
        glds16(&A[gA[p] + (koff)], &As[buf][(p * 256 + w * 64) * 8]);         \
    _Pragma("unroll")                                                         \
    for (int p = 0; p < (BN) / 64; ++p)                                       \
        glds16(&Bt[gB[p] + (koff)], &Bs[buf][(p * 256 + w * 64) * 8]);

// ---------------------------------------------------------------------------
// Fused projection GEMM. z: 0=Q 1=K_self 2=K_ctx 3=V_self 4=V_ctx
// Double-buffered, 1 barrier per K-iter. LDS 32 KB -> 5 blocks/CU.
// ---------------------------------------------------------------------------
__global__ __launch_bounds__(256) void proj_gemm(
    const f16* __restrict__ xb, const f16* __restrict__ cb,
    const f16* __restrict__ wt,
    const float* __restrict__ bq, const float* __restrict__ bks,
    const float* __restrict__ bkc, const float* __restrict__ bvs,
    const float* __restrict__ bvc,
    f16* __restrict__ qbuf, f16* __restrict__ kbuf, f16* __restrict__ vbuf)
{
    __shared__ alignas(16) f16 As[2][128 * 32];
    __shared__ alignas(16) f16 Bs[2][128 * 32];

    const int z = blockIdx.z;
    const f16* A = (z == 0 || z == 1 || z == 3) ? xb : cb;
    const int wslot = (z == 0) ? 0 : (z == 1) ? 1 : (z == 2) ? 3 : (z == 3) ? 2 : 4;
    const f16* Bt = wt + (size_t)wslot * 1048576;
    const float* bias = (z == 0) ? bq : (z == 1) ? bks : (z == 2) ? bkc
                        : (z == 3) ? bvs : bvc;
    const int roff = (z == 2 || z == 4) ? 2048 : 0;

    GEMM_PROLOGUE(128)
    f32x4 acc[4][4] = {};

    GEMM_STAGE_TO(128, 0, 0)

    for (int k0 = 0; k0 < 1024; k0 += 32) {
        const int cur = (k0 >> 5) & 1;
        __syncthreads();   // tile k0 resident; prev reads of buf cur^1 done
        if (k0 + 32 < 1024) {
            GEMM_STAGE_TO(128, cur ^ 1, k0 + 32)
        }
        f16x8 a[4], b[4];
#pragma unroll
        for (int i = 0; i < 4; ++i)
            a[i] = *(const f16x8*)&As[cur][(wm + i * 16 + l15) * 32 + qsw];
#pragma unroll
        for (int i = 0; i < 4; ++i)
            b[i] = *(const f16x8*)&Bs[cur][(wn + i * 16 + l15) * 32 + qsw];
#pragma unroll
        for (int mi = 0; mi < 4; ++mi)
#pragma unroll
            for (int ni = 0; ni < 4; ++ni)
                acc[mi][ni] = MFMA_F16(a[mi], b[ni], acc[mi][ni]);
    }

#pragma unroll
    for (int mi = 0; mi < 4; ++mi) {
#pragma unroll
        for (int r = 0; r < 4; ++r) {
            int row = m0 + wm + mi * 16 + quad * 4 + r;
            int b_ = row >> 11, tok = row & 2047;
#pragma unroll
            for (int ni = 0; ni < 4; ++ni) {
                int col = n0 + wn + ni * 16 + l15;
                float v = acc[mi][ni][r] + bias[col];
                int bh = b_ * 16 + (col >> 6);
                int tg = roff + tok;
                if (z == 0) {
                    qbuf[((size_t)bh * 2048 + tok) * 64 + (col & 63)] = (f16)(v * QSCALE);
                } else if (z <= 2) {
                    kbuf[(size_t)bh * 262144 + (size_t)(tg >> 6) * 4096
                         + (size_t)((col >> 5) & 1) * 2048 + (tg & 63) * 32 + (col & 31)] = (f16)v;
                } else {
                    vbuf[(size_t)bh * 262144 + (size_t)tg * 64 + (col & 63)] = (f16)v;
                }
            }
        }
    }
}

// ---------------------------------------------------------------------------
// V transpose: vbuf [bh][4096][64] -> vt tiles [bh][kt64][kks2][d64][32kk]
// ---------------------------------------------------------------------------
__global__ __launch_bounds__(256) void transpose_v(
    const f16* __restrict__ vbuf, f16* __restrict__ vt)
{
    const int t = threadIdx.x;
    const int mt = t >> 3, md = t & 7;
    const int tok0 = blockIdx.x * 256 + mt * 8;
    const int z = blockIdx.y;                   // bh
    f16x8 in[8];
#pragma unroll
    for (int i = 0; i < 8; ++i)
        in[i] = *(const f16x8*)&vbuf[((size_t)z * 4096 + tok0 + i) * 64 + md * 8];
    f16x8 ov[8];
#pragma unroll
    for (int j = 0; j < 8; ++j)
#pragma unroll
        for (int i = 0; i < 8; ++i) ov[j][i] = in[i][j];
    const int kt = tok0 >> 6, kks = (tok0 >> 5) & 1, kko = tok0 & 31;
#pragma unroll
    for (int j = 0; j < 8; ++j)
        *(f16x8*)&vt[(size_t)z * 262144 + (size_t)kt * 4096 + kks * 2048
                     + (md * 8 + j) * 32 + kko] = ov[j];
}

// ---------------------------------------------------------------------------
// Flash attention, S^T form, TK=64, SPLIT-K4 (16 key-tiles per block).
// R6/R7: NO LDS, NO BARRIERS. Each wave loads its K/V MFMA fragments
// directly from the tiled global buffers (linear fragment addressing; L1
// shares across the CU's blocks, L2 via XCD-chunked swizzle). Waves fully
// independent -> stalls hide via drift. Wave owns 32 q-rows = 32 output
// columns of 32x32 MFMA.
// Per tile, per mt of 2:
//   S^T = sum_kc mfma32(Kfrag, Qfrag); pe = exp2(S); l_part += tree-sum
//   pack + permlane32_swap -> P frags; O^T += mfma32(Vfrag, Pfrag)
// Grid: 2048 linear; swz=(lin&7)*256+(lin>>3) (bijective, 2048%8==0):
// qt fastest within an XCD chunk -> resident set 16 (bh,sp) splits = 4MB/XCD.
// ---------------------------------------------------------------------------
__global__ __launch_bounds__(256, 4) void attn_kernel(
    const f16* __restrict__ q, const f16* __restrict__ kb,
    const f16* __restrict__ vtb, f16* __restrict__ o01,
    f16* __restrict__ o23, float* __restrict__ lsplit)
{
    const int tid = threadIdx.x;
    const int w = tid >> 6, lane = tid & 63;
    const int l31 = lane & 31, h = lane >> 5;

    const int lin = blockIdx.x;
    const int swz = (lin & 7) * 256 + (lin >> 3);
    const int qt = swz & 15, bh = (swz >> 4) & 31, sp = swz >> 9;
    const int qbase = qt * 128;

    // Q fragments: B[q = l31][k = kc*16 + h*8 + j]
    f16x8 qa[4];
    {
        const size_t qrow = ((size_t)bh * 2048 + qbase + w * 32 + l31) * 64;
#pragma unroll
        for (int kc = 0; kc < 4; ++kc)
            qa[kc] = *(const f16x8*)&q[qrow + kc * 16 + h * 8];
    }

    f32x16 o_acc[2] = {};   // O^T[d = db*32 + (reg&3)+8*(reg>>2)+4h][q = l31]
    float l_part = 0.f;

    // per-lane fragment base (f16 units): tile + row(l31)*32 + h*8
    const f16* kp = kb  + (size_t)bh * 262144 + (size_t)sp * 65536 + l31 * 32 + h * 8;
    const f16* vp = vtb + (size_t)bh * 262144 + (size_t)sp * 65536 + l31 * 32 + h * 8;

#pragma unroll 2
    for (int kt = 0; kt < 16; ++kt) {
#pragma unroll
        for (int mt = 0; mt < 2; ++mt) {
            // K frags: [tok = mt*32+l31][k = kc*16+h*8] -> kp + ks*2048 +
            //   mt*1024 + (kc&1)*16   (f16 units; imm-offset foldable)
            f16x8 ka[4];
#pragma unroll
            for (int kc = 0; kc < 4; ++kc)
                ka[kc] = *(const f16x8*)&kp[(kc >> 1) * 2048 + mt * 1024 + (kc & 1) * 16];
            // V frags for kchunks 2mt, 2mt+1: vp + kks*2048 + db*1024 + (kch&1)*16
            f16x8 va[2][2];
#pragma unroll
            for (int c = 0; c < 2; ++c)
#pragma unroll
                for (int db = 0; db < 2; ++db) {
                    const int kchunk = mt * 2 + c;
                    va[c][db] = *(const f16x8*)&vp[(kchunk >> 1) * 2048
                                 + db * 1024 + (kchunk & 1) * 16];
                }

            f32x16 s = {};
            __builtin_amdgcn_s_setprio(1);
#pragma unroll
            for (int kc = 0; kc < 4; ++kc)
                s = MFMA32_F16(ka[kc], qa[kc], s);
            __builtin_amdgcn_s_setprio(0);

            float pe[16];
#pragma unroll
            for (int i = 0; i < 16; ++i) pe[i] = __builtin_amdgcn_exp2f(s[i]);

            {   // l partial: rows with bit2 == h (partner half added in epilogue)
                float t0 = (pe[0] + pe[1]) + (pe[2] + pe[3]);
                float t1 = (pe[4] + pe[5]) + (pe[6] + pe[7]);
                float t2 = (pe[8] + pe[9]) + (pe[10] + pe[11]);
                float t3 = (pe[12] + pe[13]) + (pe[14] + pe[15]);
                l_part += (t0 + t1) + (t2 + t3);
            }

#pragma unroll
            for (int c = 0; c < 2; ++c) {
                const int cb = c * 8;
                unsigned X0 = pk16(pe[cb + 0], pe[cb + 1]);
                unsigned X1 = pk16(pe[cb + 2], pe[cb + 3]);
                unsigned Y0 = pk16(pe[cb + 4], pe[cb + 5]);
                unsigned Y1 = pk16(pe[cb + 6], pe[cb + 7]);
                // dst.hi <-> src.lo: r[0] = {X.lo, Y.lo}, r[1] = {X.hi, Y.hi}
                auto r0 = __builtin_amdgcn_permlane32_swap(X0, Y0, false, false);
                auto r1 = __builtin_amdgcn_permlane32_swap(X1, Y1, false, false);
                u32x4v pw;
                pw[0] = r0[0]; pw[1] = r1[0]; pw[2] = r0[1]; pw[3] = r1[1];
                f16x8 pfrag = __builtin_bit_cast(f16x8, pw);  // B[q][kk = 8h+j]

                __builtin_amdgcn_s_setprio(1);
#pragma unroll
                for (int db = 0; db < 2; ++db)
                    o_acc[db] = MFMA32_F16(va[c][db], pfrag, o_acc[db]);
                __builtin_amdgcn_s_setprio(0);
            }
        }
        kp += 4096; vp += 4096;
    }

    // epilogue: l = own half + partner half; write O^/l (f16) and l (f32).
    float lf = l_part + __shfl_xor(l_part, 32, 64);
    float inv = 1.0f / lf;
    const int row = w * 32 + l31;
    if (h == 0) lsplit[((size_t)sp * 32 + bh) * 2048 + qbase + row] = lf;
    f16* ob = (sp & 2) ? o23 : o01;
    const size_t obase =
        (((size_t)(sp & 1) * 32 + bh) * 2048 + qbase + row) * 64;
#pragma unroll
    for (int db = 0; db < 2; ++db) {
#pragma unroll
        for (int g = 0; g < 4; ++g) {
            f16x4v ov;
#pragma unroll
            for (int i = 0; i < 4; ++i)
                ov[i] = (f16)(o_acc[db][g * 4 + i] * inv);
            *(f16x4v*)&ob[obase + db * 32 + g * 8 + h * 4] = ov;
        }
    }
}

// ---------------------------------------------------------------------------
// combine: abuf[b*2048+row][h*64+d] = sum_s l_s*O_s^ / sum_s l_s
// ---------------------------------------------------------------------------
__global__ __launch_bounds__(256) void combine(
    const f16* __restrict__ o01, const f16* __restrict__ o23,
    const float* __restrict__ lsplit, f16* __restrict__ abuf)
{
    int idx = blockIdx.x * 256 + threadIdx.x;     // 524288 total
    int d8 = idx & 7;
    int row = (idx >> 3) & 2047;
    int bh = idx >> 14;
    int b = bh >> 4, h = bh & 15;
    const size_t rb = ((size_t)bh * 2048 + row) * 64 + d8 * 8;
    const size_t spstride = (size_t)32 * 2048 * 64;
    const int lrow = bh * 2048 + row;
    float l0 = lsplit[lrow];
    float l1 = lsplit[65536 + lrow];
    float l2 = lsplit[131072 + lrow];
    float l3 = lsplit[196608 + lrow];
    float inv = 1.0f / (((l0 + l1) + (l2 + l3)));
    f16x8 a0 = *(const f16x8*)&o01[rb];
    f16x8 a1 = *(const f16x8*)&o01[spstride + rb];
    f16x8 a2 = *(const f16x8*)&o23[rb];
    f16x8 a3 = *(const f16x8*)&o23[spstride + rb];
    float w0 = l0 * inv, w1 = l1 * inv, w2 = l2 * inv, w3 = l3 * inv;
    f16x8 out;
#pragma unroll
    for (int j = 0; j < 8; ++j)
        out[j] = (f16)(w0 * (float)a0[j] + w1 * (float)a1[j]
                     + w2 * (float)a2[j] + w3 * (float)a3[j]);
    *(f16x8*)&abuf[((size_t)(b * 2048 + row)) * 1024 + h * 64 + d8 * 8] = out;
}

// ---------------------------------------------------------------------------
// Output GEMM, 128x64 tiles, fp32 out. Double-buffered 1-barrier K-loop.
// LDS = 2*(8+4) KB = 24 KB.
// ---------------------------------------------------------------------------
__global__ __launch_bounds__(256) void out_gemm(
    const f16* __restrict__ abuf, const f16* __restrict__ wt5,
    const float* __restrict__ bo, float* __restrict__ out)
{
    __shared__ alignas(16) f16 As[2][128 * 32];
    __shared__ alignas(16) f16 Bs[2][64 * 32];

    const f16* A = abuf;
    const f16* Bt = wt5;

    GEMM_PROLOGUE(64)
    f32x4 acc[4][2] = {};

    GEMM_STAGE_TO(64, 0, 0)

    for (int k0 = 0; k0 < 1024; k0 += 32) {
        const int cur = (k0 >> 5) & 1;
        __syncthreads();   // tile k0 resident; prev reads of buf cur^1 done
        if (k0 + 32 < 1024) {
            GEMM_STAGE_TO(64, cur ^ 1, k0 + 32)
        }
        f16x8 a[4], b[2];
#pragma unroll
        for (int i = 0; i < 4; ++i)
            a[i] = *(const f16x8*)&As[cur][(wm + i * 16 + l15) * 32 + qsw];
#pragma unroll
        for (int i = 0; i < 2; ++i)
            b[i] = *(const f16x8*)&Bs[cur][(wn + i * 16 + l15) * 32 + qsw];
#pragma unroll
        for (int mi = 0; mi < 4; ++mi)
#pragma unroll
            for (int ni = 0; ni < 2; ++ni)
                acc[mi][ni] = MFMA_F16(a[mi], b[ni], acc[mi][ni]);
    }

#pragma unroll
    for (int mi = 0; mi < 4; ++mi) {
#pragma unroll
        for (int r = 0; r < 4; ++r) {
            int row = m0 + wm + mi * 16 + quad * 4 + r;
#pragma unroll
            for (int ni = 0; ni < 2; ++ni) {
                int col = n0 + wn + ni * 16 + l15;
                out[(size_t)row * 1024 + col] = acc[mi][ni][r] + bo[col];
            }
        }
    }
}

// ---------------------------------------------------------------------------
// Host launcher
// ---------------------------------------------------------------------------
extern "C" void kernel_launch(void* const* d_in, const int* in_sizes, int n_in,
                              void* d_out, int out_size, void* d_ws, size_t ws_size,
                              hipStream_t stream)
{
    (void)in_sizes; (void)n_in; (void)out_size; (void)ws_size;

    const float* x    = (const float*)d_in[0];
    const float* ctx  = (const float*)d_in[1];
    const float* Wq   = (const float*)d_in[2];  const float* bq  = (const float*)d_in[3];
    const float* Wks  = (const float*)d_in[4];  const float* bks = (const float*)d_in[5];
    const float* Wvs  = (const float*)d_in[6];  const float* bvs = (const float*)d_in[7];
    const float* Wkc  = (const float*)d_in[8];  const float* bkc = (const float*)d_in[9];
    const float* Wvc  = (const float*)d_in[10]; const float* bvc = (const float*)d_in[11];
    const float* Wo   = (const float*)d_in[12]; const float* bo  = (const float*)d_in[13];

    char* ws = (char*)d_ws;
    f16*   xb     = (f16*)(ws + 0);          //  8 MB (dead after proj)
    f16*   cb     = (f16*)(ws + 8388608);    //  8 MB (dead after proj)
    f16*   vt     = (f16*)(ws + 0);          // 16 MB V^T tiles, reuses xb+cb
    f16*   wt     = (f16*)(ws + 16777216);   // 12 MB 6 x [1024][1024]
    float* lsplit = (float*)(ws + 16777216); // 1 MB, reuses dead Wq^T slice
    f16*   qbuf   = (f16*)(ws + 29360128);   //  8 MB [bh][2048][64]
    f16*   kbuf   = (f16*)(ws + 37748736);   // 16 MB K tiles
    f16*   vbuf   = (f16*)(ws + 54525952);   // 16 MB (dead after transpose_v)
    f16*   o01    = (f16*)(ws + 54525952);   // 16 MB sp0/sp1 partials @ vbuf
    f16*   abuf   = (f16*)(ws + 71303168);   //  8 MB (end 79,691,776)
    f16*   o23    = (f16*)d_out;             // 16 MB sp2/sp3 partials @ d_out
                                             // (attn writes -> combine reads
                                             //  -> out_gemm overwrites)

    prep<<<14336, 256, 0, stream>>>((const float4*)x, (const float4*)ctx,
                                    (f16x4v*)xb, (f16x4v*)cb,
                                    Wq, Wks, Wvs, Wkc, Wvc, Wo, wt);

    proj_gemm<<<dim3(32, 8, 5), 256, 0, stream>>>(
        xb, cb, wt, bq, bks, bkc, bvs, bvc, qbuf, kbuf, vbuf);

    transpose_v<<<dim3(16, 32), 256, 0, stream>>>(vbuf, vt);

    attn_kernel<<<2048, 256, 0, stream>>>(qbuf, kbuf, vt, o01, o23, lsplit);

    combine<<<2048, 256, 0, stream>>>(o01, o23, lsplit, abuf);

    out_gemm<<<dim3(32, 16), 256, 0, stream>>>(abuf, wt + 5 * 1048576, bo, (float*)d_out);
}

// Round 8
// 307.286 us; speedup vs baseline: 1.1539x; 1.1539x over previous
//
#include <hip/hip_runtime.h>
#include <hip/hip_bf16.h>
#include <math.h>

// ---------------------------------------------------------------------------
// JointAttention fp16 MFMA pipeline, 6 dispatches:
//   prep (fp32->fp16 x/ctx + pack W^T) -> proj (fused 5-job QKV GEMM, dbuf) ->
//   transpose_v -> flash attn (S^T, TK=64, SPLIT-K2, 32x32 MFMA, in-register
//   softmax, glds double-buffer 1-barrier) -> combine -> out GEMM (dbuf).
// R1: proj/out GEMM dbuf 1-barrier; setprio in attn.
// R2: attn single-buffer K/V + reg-staged prefetch: LDS 50->34.8KB.
// R3: attn on mfma_f32_32x32x16_f16: in-register P via permlane32_swap;
//     P_lds gone; LDS 16KB, VGPR 60 (+~48 acc). 83.5us.
// R4: split-K4 + bounds(256,8) -> acc spill regression (VGPR 32, 812MB).
// R5: split-K4 + bounds(256,4): NULL. Unified VGPR+AGPR (~124/wave) caps
//     residency at 4 waves/SIMD; grid can't add waves. ~25% barrier stall.
// R6/R7: no-LDS direct-global fragments: REFUTED (157us, MfmaUtil 18%) —
//     L2 latency (~200cy) per fragment unhidable at 3 waves/SIMD; LDS
//     staging is the latency amortizer. Reverted.
// R8: attn = R3 compute + R1 staging: K/V DOUBLE-buffer via glds, ONE
//     barrier per tile (barrier drains glds of kt + frees buf^1; issue
//     glds kt+1; compute kt). Removes R3's 2nd barrier + 4 ds_write +
//     staging regs. Split-K2 (best total). LDS 32KB (4 blocks/CU unchanged).
// Swizzle: LDS chunk col c' = c ^ ((row>>1)&3) baked into staging global addr;
//   readers XOR with ksw = (l31>>1)&3.
// Layouts:
//   qbuf [bh][2048][64]              (Q pre-scaled by 0.125*log2e)
//   kbuf [bh][kt64][ks2][tok64][32]  (8KB contiguous staging tiles)
//   vbuf [bh][4096][64]  -> dead after transpose_v, reused as osplit
//   vt   [bh][kt64][kks2][d64][32]   (8KB contiguous V^T staging tiles)
//   osplit [s2][bh][2048][64] f16 (normalized partial O)   @ vbuf region
//   lsplit [s2][bh][2048] f32 (partial softmax denom)      @ dead Wq^T region
// ---------------------------------------------------------------------------

typedef _Float16 f16;
typedef _Float16 f16x8 __attribute__((ext_vector_type(8)));
typedef _Float16 f16x4v __attribute__((ext_vector_type(4)));
typedef _Float16 f16x2 __attribute__((ext_vector_type(2)));
typedef float    f32x4 __attribute__((ext_vector_type(4)));
typedef float    f32x16 __attribute__((ext_vector_type(16)));
typedef unsigned u32x4v __attribute__((ext_vector_type(4)));

#define MFMA_F16(a, b, c)  __builtin_amdgcn_mfma_f32_16x16x32_f16((a), (b), (c), 0, 0, 0)
#define MFMA32_F16(a, b, c) __builtin_amdgcn_mfma_f32_32x32x16_f16((a), (b), (c), 0, 0, 0)

#define QSCALE 0.18033688011112042f   // 0.125 * log2(e)

__device__ __forceinline__ void glds16(const f16* g, f16* l) {
    __builtin_amdgcn_global_load_lds(
        (const __attribute__((address_space(1))) void*)g,
        (__attribute__((address_space(3))) void*)l, 16, 0, 0);
}

// RNE f32x2 -> packed f16x2 (matches prior numerics; no RTZ risk)
__device__ __forceinline__ unsigned pk16(float a, float b) {
    f16x2 t = { (f16)a, (f16)b };
    return __builtin_bit_cast(unsigned, t);
}

// ---------------------------------------------------------------------------
// prep: blocks [0,8192) convert x/ctx fp32->fp16; [8192,14336) pack 6 W^T
// ---------------------------------------------------------------------------
__global__ __launch_bounds__(256) void prep(
    const float4* __restrict__ x, const float4* __restrict__ ctx,
    f16x4v* __restrict__ xb, f16x4v* __restrict__ cb,
    const float* __restrict__ W0, const float* __restrict__ W1,
    const float* __restrict__ W2, const float* __restrict__ W3,
    const float* __restrict__ W4, const float* __restrict__ W5,
    f16* __restrict__ wt)
{
    if (blockIdx.x < 8192) {
        const int n4 = (2 * 2048 * 1024) / 4;
        int i = blockIdx.x * 256 + threadIdx.x;
        float4 v;
        f16x4v* dst;
        if (i < n4) { v = x[i];        dst = xb + i; }
        else        { v = ctx[i - n4]; dst = cb + (i - n4); }
        f16x4v h = { (f16)v.x, (f16)v.y, (f16)v.z, (f16)v.w };
        *dst = h;
        return;
    }
    const int idx = blockIdx.x - 8192;
    const int z = idx >> 10, rem = idx & 1023;
    const float* Ws[6] = { W0, W1, W2, W3, W4, W5 };
    const float* W = Ws[z];
    f16* Wt = wt + (size_t)z * (1024 * 1024);

    __shared__ float tile[32][33];
    const int tx = threadIdx.x & 31, ty = threadIdx.x >> 5;
    const int n0 = (rem & 31) * 32, k0 = (rem >> 5) * 32;

#pragma unroll
    for (int i = 0; i < 4; ++i) {
        int r = i * 8 + ty;
        tile[r][tx] = W[(size_t)(k0 + r) * 1024 + n0 + tx];
    }
    __syncthreads();
#pragma unroll
    for (int i = 0; i < 4; ++i) {
        int r = i * 8 + ty;
        Wt[(size_t)(n0 + r) * 1024 + k0 + tx] = (f16)tile[tx][r];
    }
}

// Shared GEMM prologue (128-row A tile, BN-row B tile, BK=32, swizzled glds)
#define GEMM_PROLOGUE(BN)                                                     \
    const int m0 = blockIdx.x * 128, n0 = blockIdx.y * (BN);                  \
    const int tid = threadIdx.x;                                              \
    const int w = tid >> 6, lane = tid & 63, quad = lane >> 4, l15 = lane & 15;\
    const int wm = (w >> 1) * 64, wn = (w & 1) * ((BN) / 2);                  \
    const int qsw = (quad ^ ((l15 >> 1) & 3)) * 8;                            \
    int gA[2], gB[(BN) / 64];                                                 \
    _Pragma("unroll")                                                         \
    for (int p = 0; p < 2; ++p) {                                             \
        int s = tid + p * 256;                                                \
        int r = (s >> 2) & 127, c = (s & 3) ^ ((s >> 3) & 3);                 \
        gA[p] = (m0 + r) * 1024 + c * 8;                                      \
    }                                                                         \
    _Pragma("unroll")                                                         \
    for (int p = 0; p < (BN) / 64; ++p) {                                     \
        int s = tid + p * 256;                                                \
        int r = (s >> 2) & ((BN) - 1), c = (s & 3) ^ ((s >> 3) & 3);          \
        gB[p] = (n0 + r) * 1024 + c * 8;                                      \
    }

// Stage K-chunk koff into LDS buffer `buf` (no barriers; caller owns sync)
#define GEMM_STAGE_TO(BN, buf, koff)                                          \
    _Pragma("unroll")                                                         \
    for (int p = 0; p < 2; ++p)                                               \
        glds16(&A[gA[p] + (koff)], &As[buf][(p * 256 + w * 64) * 8]);         \
    _Pragma("unroll")                                                         \
    for (int p = 0; p < (BN) / 64; ++p)                                       \
        glds16(&Bt[gB[p] + (koff)], &Bs[buf][(p * 256 + w * 64) * 8]);

// ---------------------------------------------------------------------------
// Fused projection GEMM. z: 0=Q 1=K_self 2=K_ctx 3=V_self 4=V_ctx
// Double-buffered, 1 barrier per K-iter. LDS 32 KB -> 5 blocks/CU.
// ---------------------------------------------------------------------------
__global__ __launch_bounds__(256) void proj_gemm(
    const f16* __restrict__ xb, const f16* __restrict__ cb,
    const f16* __restrict__ wt,
    const float* __restrict__ bq, const float* __restrict__ bks,
    const float* __restrict__ bkc, const float* __restrict__ bvs,
    const float* __restrict__ bvc,
    f16* __restrict__ qbuf, f16* __restrict__ kbuf, f16* __restrict__ vbuf)
{
    __shared__ alignas(16) f16 As[2][128 * 32];
    __shared__ alignas(16) f16 Bs[2][128 * 32];

    const int z = blockIdx.z;
    const f16* A = (z == 0 || z == 1 || z == 3) ? xb : cb;
    const int wslot = (z == 0) ? 0 : (z == 1) ? 1 : (z == 2) ? 3 : (z == 3) ? 2 : 4;
    const f16* Bt = wt + (size_t)wslot * 1048576;
    const float* bias = (z == 0) ? bq : (z == 1) ? bks : (z == 2) ? bkc
                        : (z == 3) ? bvs : bvc;
    const int roff = (z == 2 || z == 4) ? 2048 : 0;

    GEMM_PROLOGUE(128)
    f32x4 acc[4][4] = {};

    GEMM_STAGE_TO(128, 0, 0)

    for (int k0 = 0; k0 < 1024; k0 += 32) {
        const int cur = (k0 >> 5) & 1;
        __syncthreads();   // tile k0 resident; prev reads of buf cur^1 done
        if (k0 + 32 < 1024) {
            GEMM_STAGE_TO(128, cur ^ 1, k0 + 32)
        }
        f16x8 a[4], b[4];
#pragma unroll
        for (int i = 0; i < 4; ++i)
            a[i] = *(const f16x8*)&As[cur][(wm + i * 16 + l15) * 32 + qsw];
#pragma unroll
        for (int i = 0; i < 4; ++i)
            b[i] = *(const f16x8*)&Bs[cur][(wn + i * 16 + l15) * 32 + qsw];
#pragma unroll
        for (int mi = 0; mi < 4; ++mi)
#pragma unroll
            for (int ni = 0; ni < 4; ++ni)
                acc[mi][ni] = MFMA_F16(a[mi], b[ni], acc[mi][ni]);
    }

#pragma unroll
    for (int mi = 0; mi < 4; ++mi) {
#pragma unroll
        for (int r = 0; r < 4; ++r) {
            int row = m0 + wm + mi * 16 + quad * 4 + r;
            int b_ = row >> 11, tok = row & 2047;
#pragma unroll
            for (int ni = 0; ni < 4; ++ni) {
                int col = n0 + wn + ni * 16 + l15;
                float v = acc[mi][ni][r] + bias[col];
                int bh = b_ * 16 + (col >> 6);
                int tg = roff + tok;
                if (z == 0) {
                    qbuf[((size_t)bh * 2048 + tok) * 64 + (col & 63)] = (f16)(v * QSCALE);
                } else if (z <= 2) {
                    kbuf[(size_t)bh * 262144 + (size_t)(tg >> 6) * 4096
                         + (size_t)((col >> 5) & 1) * 2048 + (tg & 63) * 32 + (col & 31)] = (f16)v;
                } else {
                    vbuf[(size_t)bh * 262144 + (size_t)tg * 64 + (col & 63)] = (f16)v;
                }
            }
        }
    }
}

// ---------------------------------------------------------------------------
// V transpose: vbuf [bh][4096][64] -> vt tiles [bh][kt64][kks2][d64][32kk]
// ---------------------------------------------------------------------------
__global__ __launch_bounds__(256) void transpose_v(
    const f16* __restrict__ vbuf, f16* __restrict__ vt)
{
    const int t = threadIdx.x;
    const int mt = t >> 3, md = t & 7;
    const int tok0 = blockIdx.x * 256 + mt * 8;
    const int z = blockIdx.y;                   // bh
    f16x8 in[8];
#pragma unroll
    for (int i = 0; i < 8; ++i)
        in[i] = *(const f16x8*)&vbuf[((size_t)z * 4096 + tok0 + i) * 64 + md * 8];
    f16x8 ov[8];
#pragma unroll
    for (int j = 0; j < 8; ++j)
#pragma unroll
        for (int i = 0; i < 8; ++i) ov[j][i] = in[i][j];
    const int kt = tok0 >> 6, kks = (tok0 >> 5) & 1, kko = tok0 & 31;
#pragma unroll
    for (int j = 0; j < 8; ++j)
        *(f16x8*)&vt[(size_t)z * 262144 + (size_t)kt * 4096 + kks * 2048
                     + (md * 8 + j) * 32 + kko] = ov[j];
}

// ---------------------------------------------------------------------------
// Flash attention, S^T form, TK=64, SPLIT-K2 (each split: 32 key-tiles).
// Grid (bh=32, qt=16, s=2) = 1024 blocks = 4/CU (register-capped). 4 waves;
// wave owns 32 q-rows = the 32 columns of one 32x32 MFMA.
// R8: K/V glds DOUBLE-buffer, ONE barrier per tile:
//   barrier (drains glds of kt; certifies all waves done reading buf^1)
//   -> issue glds kt+1 into buf^1 -> compute kt from buf.
// Per tile, per mt of 2:
//   S^T[kk32][q32] = sum_kc mfma32(Kfrag[kc], Qfrag[kc])  (4 chained MFMA)
//   pe = exp2(S); l_part += tree-sum(pe)  (f32 VALU)
//   pack pairs + permlane32_swap -> PV B-operand frags
//   O^T[d][q] += mfma32(Vfrag, Pfrag)   (4 MFMA)
// No P_lds. LDS = 32 KB.
// ---------------------------------------------------------------------------
__global__ __launch_bounds__(256, 4) void attn_kernel(
    const f16* __restrict__ q, const f16* __restrict__ kb,
    const f16* __restrict__ vtb, f16* __restrict__ osplit,
    float* __restrict__ lsplit)
{
    __shared__ alignas(16) f16 K_lds[2][4096];     // [buf][ks2][tok64][32]
    __shared__ alignas(16) f16 V_lds[2][4096];     // [buf][kks2][d64][32]

    const int tid = threadIdx.x;
    const int w = tid >> 6, lane = tid & 63;
    const int l31 = lane & 31, h = lane >> 5;
    const int bh = blockIdx.x, qt = blockIdx.y, sp = blockIdx.z;
    const int qbase = qt * 128;

    // Q fragments: B[q = l31][k = kc*16 + h*8 + j]
    f16x8 qa[4];
    {
        const size_t qrow = ((size_t)bh * 2048 + qbase + w * 32 + l31) * 64;
#pragma unroll
        for (int kc = 0; kc < 4; ++kc)
            qa[kc] = *(const f16x8*)&q[qrow + kc * 16 + h * 8];
    }

    f32x16 o_acc[2] = {};   // O^T[d = db*32 + (reg&3)+8*(reg>>2)+4h][q = l31]
    float l_part = 0.f;

    const f16* ktile = kb + (size_t)bh * 262144 + (size_t)sp * 131072;
    const f16* vtile = vtb + (size_t)bh * 262144 + (size_t)sp * 131072;

    const int sco = ((tid >> 2) * 4 + ((tid & 3) ^ ((tid >> 3) & 3))) * 8;
    const int ksw = (l31 >> 1) & 3;                // staging swizzle un-XOR
    const int wslot = w * 512;

    // tile 0 -> buf 0 via async glds (drained by first loop barrier)
    glds16(ktile + sco,        &K_lds[0][wslot]);
    glds16(ktile + 2048 + sco, &K_lds[0][2048 + wslot]);
    glds16(vtile + sco,        &V_lds[0][wslot]);
    glds16(vtile + 2048 + sco, &V_lds[0][2048 + wslot]);

    for (int kt = 0; kt < 32; ++kt) {
        const int cur = kt & 1;
        const f16* Kc = K_lds[cur];
        const f16* Vc = V_lds[cur];

        __syncthreads();   // glds(kt) drained; all waves done with buf cur^1

        // prefetch tile kt+1 into buf cur^1; overlaps compute of kt
        if (kt != 31) {
            ktile += 4096; vtile += 4096;
            glds16(ktile + sco,        &K_lds[cur ^ 1][wslot]);
            glds16(ktile + 2048 + sco, &K_lds[cur ^ 1][2048 + wslot]);
            glds16(vtile + sco,        &V_lds[cur ^ 1][wslot]);
            glds16(vtile + 2048 + sco, &V_lds[cur ^ 1][2048 + wslot]);
        }

#pragma unroll
        for (int mt = 0; mt < 2; ++mt) {
            // QK^T: A = K[tok = mt*32+l31][k], B = Q[q][k]
            f32x16 s = {};
            __builtin_amdgcn_s_setprio(1);
#pragma unroll
            for (int kc = 0; kc < 4; ++kc) {
                f16x8 ka = *(const f16x8*)&Kc[(kc >> 1) * 2048
                             + (mt * 32 + l31) * 32
                             + ((((kc & 1) * 2 + h) ^ ksw)) * 8];
                s = MFMA32_F16(ka, qa[kc], s);
            }
            __builtin_amdgcn_s_setprio(0);

            float pe[16];
#pragma unroll
            for (int i = 0; i < 16; ++i) pe[i] = __builtin_amdgcn_exp2f(s[i]);

            {   // l partial: rows with bit2 == h (partner half added in epilogue)
                float t0 = (pe[0] + pe[1]) + (pe[2] + pe[3]);
                float t1 = (pe[4] + pe[5]) + (pe[6] + pe[7]);
                float t2 = (pe[8] + pe[9]) + (pe[10] + pe[11]);
                float t3 = (pe[12] + pe[13]) + (pe[14] + pe[15]);
                l_part += (t0 + t1) + (t2 + t3);
            }

#pragma unroll
            for (int c = 0; c < 2; ++c) {
                // chunk c: regs cb..cb+7 hold in-chunk kk {4h..4h+3} u {8+4h..}
                const int cb = c * 8;
                unsigned X0 = pk16(pe[cb + 0], pe[cb + 1]);
                unsigned X1 = pk16(pe[cb + 2], pe[cb + 3]);
                unsigned Y0 = pk16(pe[cb + 4], pe[cb + 5]);
                unsigned Y1 = pk16(pe[cb + 6], pe[cb + 7]);
                // dst.hi <-> src.lo: r[0] = {X.lo, Y.lo}, r[1] = {X.hi, Y.hi}
                auto r0 = __builtin_amdgcn_permlane32_swap(X0, Y0, false, false);
                auto r1 = __builtin_amdgcn_permlane32_swap(X1, Y1, false, false);
                u32x4v pw;
                pw[0] = r0[0]; pw[1] = r1[0]; pw[2] = r0[1]; pw[3] = r1[1];
                f16x8 pfrag = __builtin_bit_cast(f16x8, pw);  // B[q][kk = 8h+j]

                const int kchunk = mt * 2 + c;
                __builtin_amdgcn_s_setprio(1);
#pragma unroll
                for (int db = 0; db < 2; ++db) {
                    f16x8 va = *(const f16x8*)&Vc[(kchunk >> 1) * 2048
                                 + (db * 32 + l31) * 32
                                 + (((((kchunk & 1) * 2 + h)) ^ ksw)) * 8];
                    o_acc[db] = MFMA32_F16(va, pfrag, o_acc[db]);
                }
                __builtin_amdgcn_s_setprio(0);
            }
        }
    }

    // epilogue: l = own half + partner half; write O^/l (f16) and l (f32).
    float lf = l_part + __shfl_xor(l_part, 32, 64);
    float inv = 1.0f / lf;
    const int row = w * 32 + l31;
    const size_t sb = (size_t)(sp * 32 + bh) * 2048 + qbase;
    if (h == 0) lsplit[sb + row] = lf;
    const size_t obase = (sb + row) * 64;
#pragma unroll
    for (int db = 0; db < 2; ++db) {
#pragma unroll
        for (int g = 0; g < 4; ++g) {
            f16x4v ov;
#pragma unroll
            for (int i = 0; i < 4; ++i)
                ov[i] = (f16)(o_acc[db][g * 4 + i] * inv);
            *(f16x4v*)&osplit[obase + db * 32 + g * 8 + h * 4] = ov;
        }
    }
}

// ---------------------------------------------------------------------------
// combine: abuf[b*2048+row][h*64+d] = (l1*O1^ + l2*O2^) / (l1+l2)
// ---------------------------------------------------------------------------
__global__ __launch_bounds__(256) void combine(
    const f16* __restrict__ osplit, const float* __restrict__ lsplit,
    f16* __restrict__ abuf)
{
    int idx = blockIdx.x * 256 + threadIdx.x;     // 524288 total
    int d8 = idx & 7;
    int row = (idx >> 3) & 2047;
    int bh = idx >> 14;
    int b = bh >> 4, h = bh & 15;
    size_t base1 = ((size_t)bh * 2048 + row) * 64 + d8 * 8;
    size_t base2 = ((size_t)(32 + bh) * 2048 + row) * 64 + d8 * 8;
    float l1 = lsplit[bh * 2048 + row];
    float l2 = lsplit[65536 + bh * 2048 + row];
    float inv = 1.0f / (l1 + l2);
    float w1 = l1 * inv, w2 = l2 * inv;
    f16x8 a = *(const f16x8*)&osplit[base1];
    f16x8 c = *(const f16x8*)&osplit[base2];
    f16x8 out;
#pragma unroll
    for (int j = 0; j < 8; ++j)
        out[j] = (f16)(w1 * (float)a[j] + w2 * (float)c[j]);
    *(f16x8*)&abuf[((size_t)(b * 2048 + row)) * 1024 + h * 64 + d8 * 8] = out;
}

// ---------------------------------------------------------------------------
// Output GEMM, 128x64 tiles, fp32 out. Double-buffered 1-barrier K-loop.
// LDS = 2*(8+4) KB = 24 KB.
// ---------------------------------------------------------------------------
__global__ __launch_bounds__(256) void out_gemm(
    const f16* __restrict__ abuf, const f16* __restrict__ wt5,
    const float* __restrict__ bo, float* __restrict__ out)
{
    __shared__ alignas(16) f16 As[2][128 * 32];
    __shared__ alignas(16) f16 Bs[2][64 * 32];

    const f16* A = abuf;
    const f16* Bt = wt5;

    GEMM_PROLOGUE(64)
    f32x4 acc[4][2] = {};

    GEMM_STAGE_TO(64, 0, 0)

    for (int k0 = 0; k0 < 1024; k0 += 32) {
        const int cur = (k0 >> 5) & 1;
        __syncthreads();   // tile k0 resident; prev reads of buf cur^1 done
        if (k0 + 32 < 1024) {
            GEMM_STAGE_TO(64, cur ^ 1, k0 + 32)
        }
        f16x8 a[4], b[2];
#pragma unroll
        for (int i = 0; i < 4; ++i)
            a[i] = *(const f16x8*)&As[cur][(wm + i * 16 + l15) * 32 + qsw];
#pragma unroll
        for (int i = 0; i < 2; ++i)
            b[i] = *(const f16x8*)&Bs[cur][(wn + i * 16 + l15) * 32 + qsw];
#pragma unroll
        for (int mi = 0; mi < 4; ++mi)
#pragma unroll
            for (int ni = 0; ni < 2; ++ni)
                acc[mi][ni] = MFMA_F16(a[mi], b[ni], acc[mi][ni]);
    }

#pragma unroll
    for (int mi = 0; mi < 4; ++mi) {
#pragma unroll
        for (int r = 0; r < 4; ++r) {
            int row = m0 + wm + mi * 16 + quad * 4 + r;
#pragma unroll
            for (int ni = 0; ni < 2; ++ni) {
                int col = n0 + wn + ni * 16 + l15;
                out[(size_t)row * 1024 + col] = acc[mi][ni][r] + bo[col];
            }
        }
    }
}

// ---------------------------------------------------------------------------
// Host launcher
// ---------------------------------------------------------------------------
extern "C" void kernel_launch(void* const* d_in, const int* in_sizes, int n_in,
                              void* d_out, int out_size, void* d_ws, size_t ws_size,
                              hipStream_t stream)
{
    (void)in_sizes; (void)n_in; (void)out_size; (void)ws_size;

    const float* x    = (const float*)d_in[0];
    const float* ctx  = (const float*)d_in[1];
    const float* Wq   = (const float*)d_in[2];  const float* bq  = (const float*)d_in[3];
    const float* Wks  = (const float*)d_in[4];  const float* bks = (const float*)d_in[5];
    const float* Wvs  = (const float*)d_in[6];  const float* bvs = (const float*)d_in[7];
    const float* Wkc  = (const float*)d_in[8];  const float* bkc = (const float*)d_in[9];
    const float* Wvc  = (const float*)d_in[10]; const float* bvc = (const float*)d_in[11];
    const float* Wo   = (const float*)d_in[12]; const float* bo  = (const float*)d_in[13];

    char* ws = (char*)d_ws;
    f16*   xb     = (f16*)(ws + 0);          //  8 MB (dead after proj)
    f16*   cb     = (f16*)(ws + 8388608);    //  8 MB (dead after proj)
    f16*   vt     = (f16*)(ws + 0);          // 16 MB V^T tiles, reuses xb+cb
    f16*   wt     = (f16*)(ws + 16777216);   // 12 MB 6 x [1024][1024]
    float* lsplit = (float*)(ws + 16777216); // 512 KB, reuses dead Wq^T slice
    f16*   qbuf   = (f16*)(ws + 29360128);   //  8 MB [bh][2048][64]
    f16*   kbuf   = (f16*)(ws + 37748736);   // 16 MB K tiles
    f16*   vbuf   = (f16*)(ws + 54525952);   // 16 MB (dead after transpose_v)
    f16*   osplit = (f16*)(ws + 54525952);   // 16 MB, reuses vbuf
    f16*   abuf   = (f16*)(ws + 71303168);   //  8 MB (end 79,691,776)

    prep<<<14336, 256, 0, stream>>>((const float4*)x, (const float4*)ctx,
                                    (f16x4v*)xb, (f16x4v*)cb,
                                    Wq, Wks, Wvs, Wkc, Wvc, Wo, wt);

    proj_gemm<<<dim3(32, 8, 5), 256, 0, stream>>>(
        xb, cb, wt, bq, bks, bkc, bvs, bvc, qbuf, kbuf, vbuf);

    transpose_v<<<dim3(16, 32), 256, 0, stream>>>(vbuf, vt);

    attn_kernel<<<dim3(32, 16, 2), 256, 0, stream>>>(qbuf, kbuf, vt, osplit, lsplit);

    combine<<<2048, 256, 0, stream>>>(osplit, lsplit, abuf);

    out_gemm<<<dim3(32, 16), 256, 0, stream>>>(abuf, wt + 5 * 1048576, bo, (float*)d_out);
}

// Round 9
// 301.267 us; speedup vs baseline: 1.1770x; 1.0200x over previous
//
#include <hip/hip_runtime.h>
#include <hip/hip_bf16.h>
#include <math.h>

// ---------------------------------------------------------------------------
// JointAttention fp16 MFMA pipeline, 6 dispatches:
//   prep (fp32->fp16 x/ctx + pack W^T) -> proj (fused 5-job QKV GEMM,
//   3-buf 2-deep counted-vmcnt pipeline) -> transpose_v -> flash attn (S^T,
//   TK=64, SPLIT-K2, 32x32 MFMA, in-register softmax, glds dbuf 1-barrier)
//   -> combine -> out GEMM (3-buf 2-deep counted-vmcnt).
// R1: proj/out GEMM dbuf 1-barrier; setprio in attn.
// R2: attn single-buffer K/V + reg-staged prefetch: LDS 50->34.8KB.
// R3: attn on mfma_f32_32x32x16_f16: in-register P via permlane32_swap.
// R4: split-K4 + bounds(256,8) -> acc spill regression. R5: split-K4 NULL
//     (register-file caps residency at 4 waves/SIMD).
// R6/R7: no-LDS direct-global fragments REFUTED (latency-bound, 157us).
// R8: attn K/V glds dbuf, 1 barrier/tile. attn dropped out of top-5;
//     proj_gemm unmasked: 105.7us, MfmaUtil 17%, HBM 12% -- pure stall.
//     1-deep prefetch gives glds ~300cyc to cover ~500-900cyc latency and
//     __syncthreads drains vmcnt(0) every iter.
// R9: proj/out -> T4 counted-vmcnt pipeline: 3 LDS buffers, 2-deep
//     prefetch; per iter { s_waitcnt vmcnt(4|3) [never 0 in loop]; raw
//     s_barrier; issue glds(it+2) -> buf[(it+2)%3]; compute buf[it%3] }.
//     Each wave waits its OWN loads pre-barrier => post-barrier the tile is
//     complete across waves; buf (it+2)%3==(it-1)%3 is rewritten only after
//     the barrier certifies all waves consumed it. LDS 48KB (3 blocks/CU).
// Swizzle: LDS chunk col c' = c ^ ((row>>1)&3) baked into staging global addr;
//   readers XOR with qsw/ksw.
// Layouts:
//   qbuf [bh][2048][64]              (Q pre-scaled by 0.125*log2e)
//   kbuf [bh][kt64][ks2][tok64][32]  (8KB contiguous staging tiles)
//   vbuf [bh][4096][64]  -> dead after transpose_v, reused as osplit
//   vt   [bh][kt64][kks2][d64][32]   (8KB contiguous V^T staging tiles)
//   osplit [s2][bh][2048][64] f16 (normalized partial O)   @ vbuf region
//   lsplit [s2][bh][2048] f32 (partial softmax denom)      @ dead Wq^T region
// ---------------------------------------------------------------------------

typedef _Float16 f16;
typedef _Float16 f16x8 __attribute__((ext_vector_type(8)));
typedef _Float16 f16x4v __attribute__((ext_vector_type(4)));
typedef _Float16 f16x2 __attribute__((ext_vector_type(2)));
typedef float    f32x4 __attribute__((ext_vector_type(4)));
typedef float    f32x16 __attribute__((ext_vector_type(16)));
typedef unsigned u32x4v __attribute__((ext_vector_type(4)));

#define MFMA_F16(a, b, c)  __builtin_amdgcn_mfma_f32_16x16x32_f16((a), (b), (c), 0, 0, 0)
#define MFMA32_F16(a, b, c) __builtin_amdgcn_mfma_f32_32x32x16_f16((a), (b), (c), 0, 0, 0)

#define QSCALE 0.18033688011112042f   // 0.125 * log2(e)

__device__ __forceinline__ void glds16(const f16* g, f16* l) {
    __builtin_amdgcn_global_load_lds(
        (const __attribute__((address_space(1))) void*)g,
        (__attribute__((address_space(3))) void*)l, 16, 0, 0);
}

// RNE f32x2 -> packed f16x2 (matches prior numerics; no RTZ risk)
__device__ __forceinline__ unsigned pk16(float a, float b) {
    f16x2 t = { (f16)a, (f16)b };
    return __builtin_bit_cast(unsigned, t);
}

// ---------------------------------------------------------------------------
// prep: blocks [0,8192) convert x/ctx fp32->fp16; [8192,14336) pack 6 W^T
// ---------------------------------------------------------------------------
__global__ __launch_bounds__(256) void prep(
    const float4* __restrict__ x, const float4* __restrict__ ctx,
    f16x4v* __restrict__ xb, f16x4v* __restrict__ cb,
    const float* __restrict__ W0, const float* __restrict__ W1,
    const float* __restrict__ W2, const float* __restrict__ W3,
    const float* __restrict__ W4, const float* __restrict__ W5,
    f16* __restrict__ wt)
{
    if (blockIdx.x < 8192) {
        const int n4 = (2 * 2048 * 1024) / 4;
        int i = blockIdx.x * 256 + threadIdx.x;
        float4 v;
        f16x4v* dst;
        if (i < n4) { v = x[i];        dst = xb + i; }
        else        { v = ctx[i - n4]; dst = cb + (i - n4); }
        f16x4v h = { (f16)v.x, (f16)v.y, (f16)v.z, (f16)v.w };
        *dst = h;
        return;
    }
    const int idx = blockIdx.x - 8192;
    const int z = idx >> 10, rem = idx & 1023;
    const float* Ws[6] = { W0, W1, W2, W3, W4, W5 };
    const float* W = Ws[z];
    f16* Wt = wt + (size_t)z * (1024 * 1024);

    __shared__ float tile[32][33];
    const int tx = threadIdx.x & 31, ty = threadIdx.x >> 5;
    const int n0 = (rem & 31) * 32, k0 = (rem >> 5) * 32;

#pragma unroll
    for (int i = 0; i < 4; ++i) {
        int r = i * 8 + ty;
        tile[r][tx] = W[(size_t)(k0 + r) * 1024 + n0 + tx];
    }
    __syncthreads();
#pragma unroll
    for (int i = 0; i < 4; ++i) {
        int r = i * 8 + ty;
        Wt[(size_t)(n0 + r) * 1024 + k0 + tx] = (f16)tile[tx][r];
    }
}

// Shared GEMM prologue (128-row A tile, BN-row B tile, BK=32, swizzled glds)
#define GEMM_PROLOGUE(BN)                                                     \
    const int m0 = blockIdx.x * 128, n0 = blockIdx.y * (BN);                  \
    const int tid = threadIdx.x;                                              \
    const int w = tid >> 6, lane = tid & 63, quad = lane >> 4, l15 = lane & 15;\
    const int wm = (w >> 1) * 64, wn = (w & 1) * ((BN) / 2);                  \
    const int qsw = (quad ^ ((l15 >> 1) & 3)) * 8;                            \
    int gA[2], gB[(BN) / 64];                                                 \
    _Pragma("unroll")                                                         \
    for (int p = 0; p < 2; ++p) {                                             \
        int s = tid + p * 256;                                                \
        int r = (s >> 2) & 127, c = (s & 3) ^ ((s >> 3) & 3);                 \
        gA[p] = (m0 + r) * 1024 + c * 8;                                      \
    }                                                                         \
    _Pragma("unroll")                                                         \
    for (int p = 0; p < (BN) / 64; ++p) {                                     \
        int s = tid + p * 256;                                                \
        int r = (s >> 2) & ((BN) - 1), c = (s & 3) ^ ((s >> 3) & 3);          \
        gB[p] = (n0 + r) * 1024 + c * 8;                                      \
    }

// Stage K-chunk koff into LDS buffer `buf` (no barriers; caller owns sync)
#define GEMM_STAGE_TO(BN, buf, koff)                                          \
    _Pragma("unroll")                                                         \
    for (int p = 0; p < 2; ++p)                                               \
        glds16(&A[gA[p] + (koff)], &As[buf][(p * 256 + w * 64) * 8]);         \
    _Pragma("unroll")                                                         \
    for (int p = 0; p < (BN) / 64; ++p)                                       \
        glds16(&Bt[gB[p] + (koff)], &Bs[buf][(p * 256 + w * 64) * 8]);

// ---------------------------------------------------------------------------
// Fused projection GEMM. z: 0=Q 1=K_self 2=K_ctx 3=V_self 4=V_ctx
// R9: 3-buffer 2-deep counted-vmcnt pipeline (T4). 4 glds/stage ->
// steady-state wait = vmcnt(4) (tile it+1 in flight). LDS 48KB, 3 blocks/CU.
// ---------------------------------------------------------------------------
__global__ __launch_bounds__(256) void proj_gemm(
    const f16* __restrict__ xb, const f16* __restrict__ cb,
    const f16* __restrict__ wt,
    const float* __restrict__ bq, const float* __restrict__ bks,
    const float* __restrict__ bkc, const float* __restrict__ bvs,
    const float* __restrict__ bvc,
    f16* __restrict__ qbuf, f16* __restrict__ kbuf, f16* __restrict__ vbuf)
{
    __shared__ alignas(16) f16 As[3][128 * 32];
    __shared__ alignas(16) f16 Bs[3][128 * 32];

    const int z = blockIdx.z;
    const f16* A = (z == 0 || z == 1 || z == 3) ? xb : cb;
    const int wslot = (z == 0) ? 0 : (z == 1) ? 1 : (z == 2) ? 3 : (z == 3) ? 2 : 4;
    const f16* Bt = wt + (size_t)wslot * 1048576;
    const float* bias = (z == 0) ? bq : (z == 1) ? bks : (z == 2) ? bkc
                        : (z == 3) ? bvs : bvc;
    const int roff = (z == 2 || z == 4) ? 2048 : 0;

    GEMM_PROLOGUE(128)
    f32x4 acc[4][4] = {};

    GEMM_STAGE_TO(128, 0, 0)
    GEMM_STAGE_TO(128, 1, 32)

    for (int it = 0; it < 32; ++it) {
        // wait own glds(it) done (tile it+1's 4 loads may stay in flight)
        if (it < 31) { asm volatile("s_waitcnt vmcnt(4)" ::: "memory"); }
        else         { asm volatile("s_waitcnt vmcnt(0)" ::: "memory"); }
        __builtin_amdgcn_s_barrier();   // all waves' tile-it loads complete;
                                        // all waves done reading buf (it+2)%3
        if (it + 2 < 32) {
            GEMM_STAGE_TO(128, (it + 2) % 3, (it + 2) * 32)
        }
        const f16* Asc = As[it % 3];
        const f16* Bsc = Bs[it % 3];
        f16x8 a[4], b[4];
#pragma unroll
        for (int i = 0; i < 4; ++i)
            a[i] = *(const f16x8*)&Asc[(wm + i * 16 + l15) * 32 + qsw];
#pragma unroll
        for (int i = 0; i < 4; ++i)
            b[i] = *(const f16x8*)&Bsc[(wn + i * 16 + l15) * 32 + qsw];
#pragma unroll
        for (int mi = 0; mi < 4; ++mi)
#pragma unroll
            for (int ni = 0; ni < 4; ++ni)
                acc[mi][ni] = MFMA_F16(a[mi], b[ni], acc[mi][ni]);
    }

#pragma unroll
    for (int mi = 0; mi < 4; ++mi) {
#pragma unroll
        for (int r = 0; r < 4; ++r) {
            int row = m0 + wm + mi * 16 + quad * 4 + r;
            int b_ = row >> 11, tok = row & 2047;
#pragma unroll
            for (int ni = 0; ni < 4; ++ni) {
                int col = n0 + wn + ni * 16 + l15;
                float v = acc[mi][ni][r] + bias[col];
                int bh = b_ * 16 + (col >> 6);
                int tg = roff + tok;
                if (z == 0) {
                    qbuf[((size_t)bh * 2048 + tok) * 64 + (col & 63)] = (f16)(v * QSCALE);
                } else if (z <= 2) {
                    kbuf[(size_t)bh * 262144 + (size_t)(tg >> 6) * 4096
                         + (size_t)((col >> 5) & 1) * 2048 + (tg & 63) * 32 + (col & 31)] = (f16)v;
                } else {
                    vbuf[(size_t)bh * 262144 + (size_t)tg * 64 + (col & 63)] = (f16)v;
                }
            }
        }
    }
}

// ---------------------------------------------------------------------------
// V transpose: vbuf [bh][4096][64] -> vt tiles [bh][kt64][kks2][d64][32kk]
// ---------------------------------------------------------------------------
__global__ __launch_bounds__(256) void transpose_v(
    const f16* __restrict__ vbuf, f16* __restrict__ vt)
{
    const int t = threadIdx.x;
    const int mt = t >> 3, md = t & 7;
    const int tok0 = blockIdx.x * 256 + mt * 8;
    const int z = blockIdx.y;                   // bh
    f16x8 in[8];
#pragma unroll
    for (int i = 0; i < 8; ++i)
        in[i] = *(const f16x8*)&vbuf[((size_t)z * 4096 + tok0 + i) * 64 + md * 8];
    f16x8 ov[8];
#pragma unroll
    for (int j = 0; j < 8; ++j)
#pragma unroll
        for (int i = 0; i < 8; ++i) ov[j][i] = in[i][j];
    const int kt = tok0 >> 6, kks = (tok0 >> 5) & 1, kko = tok0 & 31;
#pragma unroll
    for (int j = 0; j < 8; ++j)
        *(f16x8*)&vt[(size_t)z * 262144 + (size_t)kt * 4096 + kks * 2048
                     + (md * 8 + j) * 32 + kko] = ov[j];
}

// ---------------------------------------------------------------------------
// Flash attention, S^T form, TK=64, SPLIT-K2 (each split: 32 key-tiles).
// Grid (bh=32, qt=16, s=2) = 1024 blocks = 4/CU (register-capped). 4 waves;
// wave owns 32 q-rows = the 32 columns of one 32x32 MFMA.
// R8: K/V glds DOUBLE-buffer, ONE barrier per tile.
// ---------------------------------------------------------------------------
__global__ __launch_bounds__(256, 4) void attn_kernel(
    const f16* __restrict__ q, const f16* __restrict__ kb,
    const f16* __restrict__ vtb, f16* __restrict__ osplit,
    float* __restrict__ lsplit)
{
    __shared__ alignas(16) f16 K_lds[2][4096];     // [buf][ks2][tok64][32]
    __shared__ alignas(16) f16 V_lds[2][4096];     // [buf][kks2][d64][32]

    const int tid = threadIdx.x;
    const int w = tid >> 6, lane = tid & 63;
    const int l31 = lane & 31, h = lane >> 5;
    const int bh = blockIdx.x, qt = blockIdx.y, sp = blockIdx.z;
    const int qbase = qt * 128;

    // Q fragments: B[q = l31][k = kc*16 + h*8 + j]
    f16x8 qa[4];
    {
        const size_t qrow = ((size_t)bh * 2048 + qbase + w * 32 + l31) * 64;
#pragma unroll
        for (int kc = 0; kc < 4; ++kc)
            qa[kc] = *(const f16x8*)&q[qrow + kc * 16 + h * 8];
    }

    f32x16 o_acc[2] = {};   // O^T[d = db*32 + (reg&3)+8*(reg>>2)+4h][q = l31]
    float l_part = 0.f;

    const f16* ktile = kb + (size_t)bh * 262144 + (size_t)sp * 131072;
    const f16* vtile = vtb + (size_t)bh * 262144 + (size_t)sp * 131072;

    const int sco = ((tid >> 2) * 4 + ((tid & 3) ^ ((tid >> 3) & 3))) * 8;
    const int ksw = (l31 >> 1) & 3;                // staging swizzle un-XOR
    const int wslot = w * 512;

    // tile 0 -> buf 0 via async glds (drained by first loop barrier)
    glds16(ktile + sco,        &K_lds[0][wslot]);
    glds16(ktile + 2048 + sco, &K_lds[0][2048 + wslot]);
    glds16(vtile + sco,        &V_lds[0][wslot]);
    glds16(vtile + 2048 + sco, &V_lds[0][2048 + wslot]);

    for (int kt = 0; kt < 32; ++kt) {
        const int cur = kt & 1;
        const f16* Kc = K_lds[cur];
        const f16* Vc = V_lds[cur];

        __syncthreads();   // glds(kt) drained; all waves done with buf cur^1

        // prefetch tile kt+1 into buf cur^1; overlaps compute of kt
        if (kt != 31) {
            ktile += 4096; vtile += 4096;
            glds16(ktile + sco,        &K_lds[cur ^ 1][wslot]);
            glds16(ktile + 2048 + sco, &K_lds[cur ^ 1][2048 + wslot]);
            glds16(vtile + sco,        &V_lds[cur ^ 1][wslot]);
            glds16(vtile + 2048 + sco, &V_lds[cur ^ 1][2048 + wslot]);
        }

#pragma unroll
        for (int mt = 0; mt < 2; ++mt) {
            // QK^T: A = K[tok = mt*32+l31][k], B = Q[q][k]
            f32x16 s = {};
            __builtin_amdgcn_s_setprio(1);
#pragma unroll
            for (int kc = 0; kc < 4; ++kc) {
                f16x8 ka = *(const f16x8*)&Kc[(kc >> 1) * 2048
                             + (mt * 32 + l31) * 32
                             + ((((kc & 1) * 2 + h) ^ ksw)) * 8];
                s = MFMA32_F16(ka, qa[kc], s);
            }
            __builtin_amdgcn_s_setprio(0);

            float pe[16];
#pragma unroll
            for (int i = 0; i < 16; ++i) pe[i] = __builtin_amdgcn_exp2f(s[i]);

            {   // l partial: rows with bit2 == h (partner half added in epilogue)
                float t0 = (pe[0] + pe[1]) + (pe[2] + pe[3]);
                float t1 = (pe[4] + pe[5]) + (pe[6] + pe[7]);
                float t2 = (pe[8] + pe[9]) + (pe[10] + pe[11]);
                float t3 = (pe[12] + pe[13]) + (pe[14] + pe[15]);
                l_part += (t0 + t1) + (t2 + t3);
            }

#pragma unroll
            for (int c = 0; c < 2; ++c) {
                // chunk c: regs cb..cb+7 hold in-chunk kk {4h..4h+3} u {8+4h..}
                const int cb = c * 8;
                unsigned X0 = pk16(pe[cb + 0], pe[cb + 1]);
                unsigned X1 = pk16(pe[cb + 2], pe[cb + 3]);
                unsigned Y0 = pk16(pe[cb + 4], pe[cb + 5]);
                unsigned Y1 = pk16(pe[cb + 6], pe[cb + 7]);
                // dst.hi <-> src.lo: r[0] = {X.lo, Y.lo}, r[1] = {X.hi, Y.hi}
                auto r0 = __builtin_amdgcn_permlane32_swap(X0, Y0, false, false);
                auto r1 = __builtin_amdgcn_permlane32_swap(X1, Y1, false, false);
                u32x4v pw;
                pw[0] = r0[0]; pw[1] = r1[0]; pw[2] = r0[1]; pw[3] = r1[1];
                f16x8 pfrag = __builtin_bit_cast(f16x8, pw);  // B[q][kk = 8h+j]

                const int kchunk = mt * 2 + c;
                __builtin_amdgcn_s_setprio(1);
#pragma unroll
                for (int db = 0; db < 2; ++db) {
                    f16x8 va = *(const f16x8*)&Vc[(kchunk >> 1) * 2048
                                 + (db * 32 + l31) * 32
                                 + (((((kchunk & 1) * 2 + h)) ^ ksw)) * 8];
                    o_acc[db] = MFMA32_F16(va, pfrag, o_acc[db]);
                }
                __builtin_amdgcn_s_setprio(0);
            }
        }
    }

    // epilogue: l = own half + partner half; write O^/l (f16) and l (f32).
    float lf = l_part + __shfl_xor(l_part, 32, 64);
    float inv = 1.0f / lf;
    const int row = w * 32 + l31;
    const size_t sb = (size_t)(sp * 32 + bh) * 2048 + qbase;
    if (h == 0) lsplit[sb + row] = lf;
    const size_t obase = (sb + row) * 64;
#pragma unroll
    for (int db = 0; db < 2; ++db) {
#pragma unroll
        for (int g = 0; g < 4; ++g) {
            f16x4v ov;
#pragma unroll
            for (int i = 0; i < 4; ++i)
                ov[i] = (f16)(o_acc[db][g * 4 + i] * inv);
            *(f16x4v*)&osplit[obase + db * 32 + g * 8 + h * 4] = ov;
        }
    }
}

// ---------------------------------------------------------------------------
// combine: abuf[b*2048+row][h*64+d] = (l1*O1^ + l2*O2^) / (l1+l2)
// ---------------------------------------------------------------------------
__global__ __launch_bounds__(256) void combine(
    const f16* __restrict__ osplit, const float* __restrict__ lsplit,
    f16* __restrict__ abuf)
{
    int idx = blockIdx.x * 256 + threadIdx.x;     // 524288 total
    int d8 = idx & 7;
    int row = (idx >> 3) & 2047;
    int bh = idx >> 14;
    int b = bh >> 4, h = bh & 15;
    size_t base1 = ((size_t)bh * 2048 + row) * 64 + d8 * 8;
    size_t base2 = ((size_t)(32 + bh) * 2048 + row) * 64 + d8 * 8;
    float l1 = lsplit[bh * 2048 + row];
    float l2 = lsplit[65536 + bh * 2048 + row];
    float inv = 1.0f / (l1 + l2);
    float w1 = l1 * inv, w2 = l2 * inv;
    f16x8 a = *(const f16x8*)&osplit[base1];
    f16x8 c = *(const f16x8*)&osplit[base2];
    f16x8 out;
#pragma unroll
    for (int j = 0; j < 8; ++j)
        out[j] = (f16)(w1 * (float)a[j] + w2 * (float)c[j]);
    *(f16x8*)&abuf[((size_t)(b * 2048 + row)) * 1024 + h * 64 + d8 * 8] = out;
}

// ---------------------------------------------------------------------------
// Output GEMM, 128x64 tiles, fp32 out.
// R9: 3-buffer 2-deep counted-vmcnt pipeline (T4). 3 glds/stage ->
// steady-state wait = vmcnt(3). LDS 36KB.
// ---------------------------------------------------------------------------
__global__ __launch_bounds__(256) void out_gemm(
    const f16* __restrict__ abuf, const f16* __restrict__ wt5,
    const float* __restrict__ bo, float* __restrict__ out)
{
    __shared__ alignas(16) f16 As[3][128 * 32];
    __shared__ alignas(16) f16 Bs[3][64 * 32];

    const f16* A = abuf;
    const f16* Bt = wt5;

    GEMM_PROLOGUE(64)
    f32x4 acc[4][2] = {};

    GEMM_STAGE_TO(64, 0, 0)
    GEMM_STAGE_TO(64, 1, 32)

    for (int it = 0; it < 32; ++it) {
        if (it < 31) { asm volatile("s_waitcnt vmcnt(3)" ::: "memory"); }
        else         { asm volatile("s_waitcnt vmcnt(0)" ::: "memory"); }
        __builtin_amdgcn_s_barrier();
        if (it + 2 < 32) {
            GEMM_STAGE_TO(64, (it + 2) % 3, (it + 2) * 32)
        }
        const f16* Asc = As[it % 3];
        const f16* Bsc = Bs[it % 3];
        f16x8 a[4], b[2];
#pragma unroll
        for (int i = 0; i < 4; ++i)
            a[i] = *(const f16x8*)&Asc[(wm + i * 16 + l15) * 32 + qsw];
#pragma unroll
        for (int i = 0; i < 2; ++i)
            b[i] = *(const f16x8*)&Bsc[(wn + i * 16 + l15) * 32 + qsw];
#pragma unroll
        for (int mi = 0; mi < 4; ++mi)
#pragma unroll
            for (int ni = 0; ni < 2; ++ni)
                acc[mi][ni] = MFMA_F16(a[mi], b[ni], acc[mi][ni]);
    }

#pragma unroll
    for (int mi = 0; mi < 4; ++mi) {
#pragma unroll
        for (int r = 0; r < 4; ++r) {
            int row = m0 + wm + mi * 16 + quad * 4 + r;
#pragma unroll
            for (int ni = 0; ni < 2; ++ni) {
                int col = n0 + wn + ni * 16 + l15;
                out[(size_t)row * 1024 + col] = acc[mi][ni][r] + bo[col];
            }
        }
    }
}

// ---------------------------------------------------------------------------
// Host launcher
// ---------------------------------------------------------------------------
extern "C" void kernel_launch(void* const* d_in, const int* in_sizes, int n_in,
                              void* d_out, int out_size, void* d_ws, size_t ws_size,
                              hipStream_t stream)
{
    (void)in_sizes; (void)n_in; (void)out_size; (void)ws_size;

    const float* x    = (const float*)d_in[0];
    const float* ctx  = (const float*)d_in[1];
    const float* Wq   = (const float*)d_in[2];  const float* bq  = (const float*)d_in[3];
    const float* Wks  = (const float*)d_in[4];  const float* bks = (const float*)d_in[5];
    const float* Wvs  = (const float*)d_in[6];  const float* bvs = (const float*)d_in[7];
    const float* Wkc  = (const float*)d_in[8];  const float* bkc = (const float*)d_in[9];
    const float* Wvc  = (const float*)d_in[10]; const float* bvc = (const float*)d_in[11];
    const float* Wo   = (const float*)d_in[12]; const float* bo  = (const float*)d_in[13];

    char* ws = (char*)d_ws;
    f16*   xb     = (f16*)(ws + 0);          //  8 MB (dead after proj)
    f16*   cb     = (f16*)(ws + 8388608);    //  8 MB (dead after proj)
    f16*   vt     = (f16*)(ws + 0);          // 16 MB V^T tiles, reuses xb+cb
    f16*   wt     = (f16*)(ws + 16777216);   // 12 MB 6 x [1024][1024]
    float* lsplit = (float*)(ws + 16777216); // 512 KB, reuses dead Wq^T slice
    f16*   qbuf   = (f16*)(ws + 29360128);   //  8 MB [bh][2048][64]
    f16*   kbuf   = (f16*)(ws + 37748736);   // 16 MB K tiles
    f16*   vbuf   = (f16*)(ws + 54525952);   // 16 MB (dead after transpose_v)
    f16*   osplit = (f16*)(ws + 54525952);   // 16 MB, reuses vbuf
    f16*   abuf   = (f16*)(ws + 71303168);   //  8 MB (end 79,691,776)

    prep<<<14336, 256, 0, stream>>>((const float4*)x, (const float4*)ctx,
                                    (f16x4v*)xb, (f16x4v*)cb,
                                    Wq, Wks, Wvs, Wkc, Wvc, Wo, wt);

    proj_gemm<<<dim3(32, 8, 5), 256, 0, stream>>>(
        xb, cb, wt, bq, bks, bkc, bvs, bvc, qbuf, kbuf, vbuf);

    transpose_v<<<dim3(16, 32), 256, 0, stream>>>(vbuf, vt);

    attn_kernel<<<dim3(32, 16, 2), 256, 0, stream>>>(qbuf, kbuf, vt, osplit, lsplit);

    combine<<<2048, 256, 0, stream>>>(osplit, lsplit, abuf);

    out_gemm<<<dim3(32, 16), 256, 0, stream>>>(abuf, wt + 5 * 1048576, bo, (float*)d_out);
}